// Round 1
// baseline (242.546 us; speedup 1.0000x reference)
//
#include <hip/hip_runtime.h>

typedef __attribute__((ext_vector_type(4))) float f32x4;
typedef __attribute__((ext_vector_type(8))) short s16x8;

#define B_ 2
#define N_ 2048
#define C_ 1024
#define H_ 16
#define D_ 64

__device__ __forceinline__ unsigned short f2bf(float f) {
  union { float f; unsigned u; } v; v.f = f;
  unsigned r = v.u + 0x7fffu + ((v.u >> 16) & 1u);
  return (unsigned short)(r >> 16);
}

// ---------------------------------------------------------------------------
// Transpose + convert weights to bf16. Wq gets softmax scale folded in.
// Output WtQKV rows: [0,1024)=Wq^T, [1024,2048)=Wk^T, [2048,3072)=Wv^T.
// ---------------------------------------------------------------------------
__global__ __launch_bounds__(256) void wtrans_kernel(
    const float* __restrict__ Wq, const float* __restrict__ Wk,
    const float* __restrict__ Wv, const float* __restrict__ Wo,
    unsigned short* __restrict__ WtQKV, unsigned short* __restrict__ WtO) {
  __shared__ float lds[64][65];
  const int t = threadIdx.x;
  const int w = blockIdx.x >> 8;
  const int tile = blockIdx.x & 255;
  const int c0 = (tile >> 4) * 64, d0 = (tile & 15) * 64;
  const float* W = (w == 0) ? Wq : (w == 1) ? Wk : (w == 2) ? Wv : Wo;
  const float scale = (w == 0) ? 0.125f * 1.4426950408889634f : 1.0f;
  #pragma unroll
  for (int p = 0; p < 16; ++p) {
    int i = p * 256 + t; int r = i >> 6, cc = i & 63;
    lds[r][cc] = W[(size_t)(c0 + r) * 1024 + d0 + cc];
  }
  __syncthreads();
  #pragma unroll
  for (int p = 0; p < 16; ++p) {
    int i = p * 256 + t; int r = i >> 6, cc = i & 63;
    unsigned short v = f2bf(lds[cc][r] * scale);
    if (w < 3) WtQKV[(size_t)(w * 1024 + d0 + r) * 1024 + c0 + cc] = v;
    else       WtO[(size_t)(d0 + r) * 1024 + c0 + cc] = v;
  }
}

// ---------------------------------------------------------------------------
// GEMM C[M][N] = A[M][1024] * Bt[N][1024]^T, 128x128 tile, 4 waves (2x2),
// 16x16x32 bf16 MFMA. MODE 0: A=f32 (x), epilogue scatters bf16 Q/K/V.
// MODE 1: A=bf16 (heads), epilogue writes f32 C.
// ---------------------------------------------------------------------------
template <int MODE>
__global__ __launch_bounds__(256, 2) void gemm_kernel(
    const void* __restrict__ Ap, const unsigned short* __restrict__ Bt,
    unsigned short* __restrict__ Qh, unsigned short* __restrict__ Kh,
    unsigned short* __restrict__ Vt, float* __restrict__ Cf) {
  __shared__ unsigned short As[128 * 72];  // stride 72 halves = 144B: aligned, 2-way only
  __shared__ unsigned short Bs[128 * 72];
  const int tid = threadIdx.x;
  const int lane = tid & 63, wv = tid >> 6;
  const int g = lane >> 4, c = lane & 15;
  const int wr = wv >> 1, wc = wv & 1;
  const int am0 = blockIdx.x * 128;
  const int bn0 = blockIdx.y * 128;
  const int K = 1024;

  f32x4 acc[4][4];
  #pragma unroll
  for (int m = 0; m < 4; m++)
    #pragma unroll
    for (int n = 0; n < 4; n++) acc[m][n] = (f32x4){0.f, 0.f, 0.f, 0.f};

  for (int k0 = 0; k0 < K; k0 += 32) {
    #pragma unroll
    for (int p = 0; p < 2; ++p) {
      int i = p * 256 + tid;
      int row = i >> 2, c8 = (i & 3) << 3;
      *(s16x8*)&Bs[row * 72 + c8] =
          *(const s16x8*)&Bt[(size_t)(bn0 + row) * K + k0 + c8];
      if (MODE == 0) {
        const float* src = (const float*)Ap + (size_t)(am0 + row) * K + k0 + c8;
        float4 f0 = *(const float4*)src;
        float4 f1 = *(const float4*)(src + 4);
        s16x8 a;
        a[0] = (short)f2bf(f0.x); a[1] = (short)f2bf(f0.y);
        a[2] = (short)f2bf(f0.z); a[3] = (short)f2bf(f0.w);
        a[4] = (short)f2bf(f1.x); a[5] = (short)f2bf(f1.y);
        a[6] = (short)f2bf(f1.z); a[7] = (short)f2bf(f1.w);
        *(s16x8*)&As[row * 72 + c8] = a;
      } else {
        *(s16x8*)&As[row * 72 + c8] =
            *(const s16x8*)&((const unsigned short*)Ap)[(size_t)(am0 + row) * K + k0 + c8];
      }
    }
    __syncthreads();
    s16x8 af[4], bfr[4];
    #pragma unroll
    for (int m = 0; m < 4; m++)
      af[m] = *(const s16x8*)&As[(wr * 64 + m * 16 + c) * 72 + g * 8];
    #pragma unroll
    for (int n = 0; n < 4; n++)
      bfr[n] = *(const s16x8*)&Bs[(wc * 64 + n * 16 + c) * 72 + g * 8];
    #pragma unroll
    for (int m = 0; m < 4; m++)
      #pragma unroll
      for (int n = 0; n < 4; n++)
        acc[m][n] = __builtin_amdgcn_mfma_f32_16x16x32_bf16(af[m], bfr[n], acc[m][n], 0, 0, 0);
    __syncthreads();
  }

  #pragma unroll
  for (int m = 0; m < 4; m++) {
    #pragma unroll
    for (int n = 0; n < 4; n++) {
      f32x4 v = acc[m][n];
      int colg = bn0 + wc * 64 + n * 16 + c;
      #pragma unroll
      for (int r = 0; r < 4; ++r) {
        int row = am0 + wr * 64 + m * 16 + g * 4 + r;
        if (MODE == 1) {
          Cf[(size_t)row * 1024 + colg] = v[r];
        } else {
          int tensor = colg >> 10, cc = colg & 1023;
          int hh = cc >> 6, dd = cc & 63;
          int bb = row >> 11, tok = row & 2047;
          unsigned short val = f2bf(v[r]);
          if (tensor == 0)
            Qh[(((size_t)bb * H_ + hh) * N_ + tok) * D_ + dd] = val;
          else if (tensor == 1)
            Kh[(((size_t)bb * H_ + hh) * N_ + tok) * D_ + dd] = val;
          else
            Vt[(((size_t)bb * H_ + hh) * D_ + dd) * N_ + tok] = val;
        }
      }
    }
  }
}

// ---------------------------------------------------------------------------
// Flash attention. Grid: bh*16 + qblock. 4 waves, each owns 32 Q rows.
// K/V fragments read directly from global (L2-resident, 256KB/head).
// Softmax wave-local (exp2 domain, scale folded into Wq). P via per-wave LDS.
// ---------------------------------------------------------------------------
__global__ __launch_bounds__(256, 2) void attn_kernel(
    const unsigned short* __restrict__ Qh, const unsigned short* __restrict__ Kh,
    const unsigned short* __restrict__ Vt, unsigned short* __restrict__ heads) {
  __shared__ unsigned short Ps[4][32 * 136];  // stride 136 halves = 272B aligned, 2-way
  const int tid = threadIdx.x;
  const int lane = tid & 63, wv = tid >> 6;
  const int g = lane >> 4, c = lane & 15;
  const int bh = blockIdx.x >> 4, qb = blockIdx.x & 15;
  const int b = bh >> 4, h = bh & 15;
  const int q0 = qb * 128 + wv * 32;

  const unsigned short* Qbase = Qh + ((size_t)bh * N_ + q0) * D_;
  const unsigned short* Kbase = Kh + (size_t)bh * N_ * D_;
  const unsigned short* Vbase = Vt + (size_t)bh * D_ * N_;

  s16x8 qf[2][2];
  #pragma unroll
  for (int f = 0; f < 2; f++)
    #pragma unroll
    for (int kf = 0; kf < 2; kf++)
      qf[f][kf] = *(const s16x8*)&Qbase[(size_t)(f * 16 + c) * D_ + kf * 32 + g * 8];

  f32x4 O[2][4];
  float mrow[2][4], lrow[2][4];
  #pragma unroll
  for (int f = 0; f < 2; f++) {
    #pragma unroll
    for (int df = 0; df < 4; df++) O[f][df] = (f32x4){0.f, 0.f, 0.f, 0.f};
    #pragma unroll
    for (int r = 0; r < 4; r++) { mrow[f][r] = -1e30f; lrow[f][r] = 0.f; }
  }

  for (int t = 0; t < 16; ++t) {
    const int kv0 = t * 128;
    f32x4 s[2][8];
    #pragma unroll
    for (int cf = 0; cf < 8; ++cf) {
      s16x8 kf0 = *(const s16x8*)&Kbase[(size_t)(kv0 + cf * 16 + c) * D_ + g * 8];
      s16x8 kf1 = *(const s16x8*)&Kbase[(size_t)(kv0 + cf * 16 + c) * D_ + 32 + g * 8];
      #pragma unroll
      for (int f = 0; f < 2; ++f) {
        f32x4 z = (f32x4){0.f, 0.f, 0.f, 0.f};
        z = __builtin_amdgcn_mfma_f32_16x16x32_bf16(qf[f][0], kf0, z, 0, 0, 0);
        s[f][cf] = __builtin_amdgcn_mfma_f32_16x16x32_bf16(qf[f][1], kf1, z, 0, 0, 0);
      }
    }
    float alpha[2][4], rsum[2][4];
    #pragma unroll
    for (int f = 0; f < 2; ++f)
      #pragma unroll
      for (int r = 0; r < 4; ++r) {
        float pm = s[f][0][r];
        #pragma unroll
        for (int cf = 1; cf < 8; ++cf) pm = fmaxf(pm, s[f][cf][r]);
        pm = fmaxf(pm, __shfl_xor(pm, 1));
        pm = fmaxf(pm, __shfl_xor(pm, 2));
        pm = fmaxf(pm, __shfl_xor(pm, 4));
        pm = fmaxf(pm, __shfl_xor(pm, 8));
        float mnew = fmaxf(mrow[f][r], pm);
        alpha[f][r] = exp2f(mrow[f][r] - mnew);
        mrow[f][r] = mnew;
        rsum[f][r] = 0.f;
      }
    #pragma unroll
    for (int f = 0; f < 2; ++f)
      #pragma unroll
      for (int cf = 0; cf < 8; ++cf)
        #pragma unroll
        for (int r = 0; r < 4; ++r) {
          float p = exp2f(s[f][cf][r] - mrow[f][r]);
          rsum[f][r] += p;
          Ps[wv][(f * 16 + g * 4 + r) * 136 + cf * 16 + c] = f2bf(p);
        }
    #pragma unroll
    for (int f = 0; f < 2; ++f)
      #pragma unroll
      for (int r = 0; r < 4; ++r) {
        float rs = rsum[f][r];
        rs += __shfl_xor(rs, 1);
        rs += __shfl_xor(rs, 2);
        rs += __shfl_xor(rs, 4);
        rs += __shfl_xor(rs, 8);
        lrow[f][r] = lrow[f][r] * alpha[f][r] + rs;
        #pragma unroll
        for (int df = 0; df < 4; ++df) O[f][df][r] *= alpha[f][r];
      }
    #pragma unroll
    for (int km = 0; km < 4; ++km) {
      s16x8 pa0 = *(const s16x8*)&Ps[wv][(c) * 136 + km * 32 + g * 8];
      s16x8 pa1 = *(const s16x8*)&Ps[wv][(16 + c) * 136 + km * 32 + g * 8];
      #pragma unroll
      for (int df = 0; df < 4; ++df) {
        s16x8 vb = *(const s16x8*)&Vbase[(size_t)(df * 16 + c) * N_ + kv0 + km * 32 + g * 8];
        O[0][df] = __builtin_amdgcn_mfma_f32_16x16x32_bf16(pa0, vb, O[0][df], 0, 0, 0);
        O[1][df] = __builtin_amdgcn_mfma_f32_16x16x32_bf16(pa1, vb, O[1][df], 0, 0, 0);
      }
    }
  }
  #pragma unroll
  for (int f = 0; f < 2; ++f)
    #pragma unroll
    for (int df = 0; df < 4; ++df)
      #pragma unroll
      for (int r = 0; r < 4; ++r) {
        float val = O[f][df][r] / lrow[f][r];
        int row = b * N_ + q0 + f * 16 + g * 4 + r;
        heads[(size_t)row * C_ + h * D_ + df * 16 + c] = f2bf(val);
      }
}

// ---------------------------------------------------------------------------
extern "C" void kernel_launch(void* const* d_in, const int* in_sizes, int n_in,
                              void* d_out, int out_size, void* d_ws, size_t ws_size,
                              hipStream_t stream) {
  const float* x  = (const float*)d_in[0];
  const float* Wq = (const float*)d_in[1];
  const float* Wk = (const float*)d_in[2];
  const float* Wv = (const float*)d_in[3];
  const float* Wo = (const float*)d_in[4];
  float* out = (float*)d_out;

  char* ws = (char*)d_ws;
  // layout (bytes): WtQKV 6291456 | WtO 2097152 | Qh 8388608 | Kh 8388608 |
  //                 Vt 8388608 | heads 8388608  => total 41943040 (~40MB)
  unsigned short* WtQKV = (unsigned short*)(ws);
  unsigned short* WtO   = (unsigned short*)(ws + 6291456);
  unsigned short* Qh    = (unsigned short*)(ws + 8388608);
  unsigned short* Kh    = (unsigned short*)(ws + 16777216);
  unsigned short* Vt    = (unsigned short*)(ws + 25165824);
  unsigned short* heads = (unsigned short*)(ws + 33554432);

  wtrans_kernel<<<dim3(1024), dim3(256), 0, stream>>>(Wq, Wk, Wv, Wo, WtQKV, WtO);
  gemm_kernel<0><<<dim3(32, 24), dim3(256), 0, stream>>>(x, WtQKV, Qh, Kh, Vt, nullptr);
  attn_kernel<<<dim3(512), dim3(256), 0, stream>>>(Qh, Kh, Vt, heads);
  gemm_kernel<1><<<dim3(32, 8), dim3(256), 0, stream>>>(heads, WtO, nullptr, nullptr, nullptr, out);
}

// Round 2
// 130.780 us; speedup vs baseline: 1.8546x; 1.8546x over previous
//
#include <hip/hip_runtime.h>

typedef __attribute__((ext_vector_type(4))) float f32x4;
typedef __attribute__((ext_vector_type(8))) short s16x8;
typedef unsigned int u32;
typedef __attribute__((ext_vector_type(4))) unsigned int u32x4;

#define B_ 2
#define N_ 2048
#define C_ 1024
#define H_ 16
#define D_ 64

__device__ __forceinline__ unsigned short f2bf(float f) {
  union { float f; unsigned u; } v; v.f = f;
  unsigned r = v.u + 0x7fffu + ((v.u >> 16) & 1u);
  return (unsigned short)(r >> 16);
}

// ---------------------------------------------------------------------------
// Transpose + convert weights to bf16. Wq gets softmax scale (and log2e) folded.
// ---------------------------------------------------------------------------
__global__ __launch_bounds__(256) void wtrans_kernel(
    const float* __restrict__ Wq, const float* __restrict__ Wk,
    const float* __restrict__ Wv, const float* __restrict__ Wo,
    unsigned short* __restrict__ WtQKV, unsigned short* __restrict__ WtO) {
  __shared__ float lds[64][65];
  const int t = threadIdx.x;
  const int w = blockIdx.x >> 8;
  const int tile = blockIdx.x & 255;
  const int c0 = (tile >> 4) * 64, d0 = (tile & 15) * 64;
  const float* W = (w == 0) ? Wq : (w == 1) ? Wk : (w == 2) ? Wv : Wo;
  const float scale = (w == 0) ? 0.125f * 1.4426950408889634f : 1.0f;
  #pragma unroll
  for (int p = 0; p < 16; ++p) {
    int i = p * 256 + t; int r = i >> 6, cc = i & 63;
    lds[r][cc] = W[(size_t)(c0 + r) * 1024 + d0 + cc];
  }
  __syncthreads();
  #pragma unroll
  for (int p = 0; p < 16; ++p) {
    int i = p * 256 + t; int r = i >> 6, cc = i & 63;
    unsigned short v = f2bf(lds[cc][r] * scale);
    if (w < 3) WtQKV[(size_t)(w * 1024 + d0 + r) * 1024 + c0 + cc] = v;
    else       WtO[(size_t)(d0 + r) * 1024 + c0 + cc] = v;
  }
}

// ---------------------------------------------------------------------------
// GEMM C[M][N] = A[M][1024] * Bt[N][1024]^T, 128x128 tile, 4 waves (2x2),
// 16x16x32 bf16 MFMA. MODE 0: A=f32 (x), epilogue scatters bf16 Q/K/V.
// MODE 1: A=bf16 (heads), epilogue writes f32 C.
// ---------------------------------------------------------------------------
template <int MODE>
__global__ __launch_bounds__(256, 2) void gemm_kernel(
    const void* __restrict__ Ap, const unsigned short* __restrict__ Bt,
    unsigned short* __restrict__ Qh, unsigned short* __restrict__ Kh,
    unsigned short* __restrict__ Vt, float* __restrict__ Cf) {
  __shared__ unsigned short As[128 * 72];
  __shared__ unsigned short Bs[128 * 72];
  const int tid = threadIdx.x;
  const int lane = tid & 63, wv = tid >> 6;
  const int g = lane >> 4, c = lane & 15;
  const int wr = wv >> 1, wc = wv & 1;
  const int am0 = blockIdx.x * 128;
  const int bn0 = blockIdx.y * 128;
  const int K = 1024;

  f32x4 acc[4][4];
  #pragma unroll
  for (int m = 0; m < 4; m++)
    #pragma unroll
    for (int n = 0; n < 4; n++) acc[m][n] = (f32x4){0.f, 0.f, 0.f, 0.f};

  for (int k0 = 0; k0 < K; k0 += 32) {
    #pragma unroll
    for (int p = 0; p < 2; ++p) {
      int i = p * 256 + tid;
      int row = i >> 2, c8 = (i & 3) << 3;
      *(s16x8*)&Bs[row * 72 + c8] =
          *(const s16x8*)&Bt[(size_t)(bn0 + row) * K + k0 + c8];
      if (MODE == 0) {
        const float* src = (const float*)Ap + (size_t)(am0 + row) * K + k0 + c8;
        float4 f0 = *(const float4*)src;
        float4 f1 = *(const float4*)(src + 4);
        s16x8 a;
        a[0] = (short)f2bf(f0.x); a[1] = (short)f2bf(f0.y);
        a[2] = (short)f2bf(f0.z); a[3] = (short)f2bf(f0.w);
        a[4] = (short)f2bf(f1.x); a[5] = (short)f2bf(f1.y);
        a[6] = (short)f2bf(f1.z); a[7] = (short)f2bf(f1.w);
        *(s16x8*)&As[row * 72 + c8] = a;
      } else {
        *(s16x8*)&As[row * 72 + c8] =
            *(const s16x8*)&((const unsigned short*)Ap)[(size_t)(am0 + row) * K + k0 + c8];
      }
    }
    __syncthreads();
    s16x8 af[4], bfr[4];
    #pragma unroll
    for (int m = 0; m < 4; m++)
      af[m] = *(const s16x8*)&As[(wr * 64 + m * 16 + c) * 72 + g * 8];
    #pragma unroll
    for (int n = 0; n < 4; n++)
      bfr[n] = *(const s16x8*)&Bs[(wc * 64 + n * 16 + c) * 72 + g * 8];
    #pragma unroll
    for (int m = 0; m < 4; m++)
      #pragma unroll
      for (int n = 0; n < 4; n++)
        acc[m][n] = __builtin_amdgcn_mfma_f32_16x16x32_bf16(af[m], bfr[n], acc[m][n], 0, 0, 0);
    __syncthreads();
  }

  #pragma unroll
  for (int m = 0; m < 4; m++) {
    #pragma unroll
    for (int n = 0; n < 4; n++) {
      f32x4 v = acc[m][n];
      int colg = bn0 + wc * 64 + n * 16 + c;
      #pragma unroll
      for (int r = 0; r < 4; ++r) {
        int row = am0 + wr * 64 + m * 16 + g * 4 + r;
        if (MODE == 1) {
          Cf[(size_t)row * 1024 + colg] = v[r];
        } else {
          int tensor = colg >> 10, cc = colg & 1023;
          int hh = cc >> 6, dd = cc & 63;
          int bb = row >> 11, tok = row & 2047;
          unsigned short val = f2bf(v[r]);
          if (tensor == 0)
            Qh[(((size_t)bb * H_ + hh) * N_ + tok) * D_ + dd] = val;
          else if (tensor == 1)
            Kh[(((size_t)bb * H_ + hh) * N_ + tok) * D_ + dd] = val;
          else
            Vt[(((size_t)bb * H_ + hh) * D_ + dd) * N_ + tok] = val;
        }
      }
    }
  }
}

// ---------------------------------------------------------------------------
// Flash attention, swapped-QK^T in-register softmax structure.
// Grid 512 (XCD-swizzled). 4 waves x 32 q-rows. KVBLK=128 per tile.
// K [128][64] and V^T [64][128] staged in LDS via global_load_lds (width 16),
// double-buffered, XOR-swizzled (pre-swizzled global source, swizzled reads).
// P stays in registers: cvt_pk_bf16 + permlane{32,16}_swap build PV B-frags.
// ---------------------------------------------------------------------------
__global__ __launch_bounds__(256, 2) void attn_kernel(
    const unsigned short* __restrict__ Qh, const unsigned short* __restrict__ Kh,
    const unsigned short* __restrict__ Vt, unsigned short* __restrict__ heads) {
  __shared__ unsigned short Ks[2][128 * 64];
  __shared__ unsigned short Vs[2][64 * 128];
  const int tid = threadIdx.x;
  const int lane = tid & 63, wv = tid >> 6;
  const int g = lane >> 4, c = lane & 15;
  const int c7 = c & 7;
  int bid = blockIdx.x;
  bid = (bid & 7) * 64 + (bid >> 3);  // XCD-chunked swizzle, 512 % 8 == 0
  const int bh = bid >> 4, qb = bid & 15;
  const int b = bh >> 4, h = bh & 15;
  const int q0 = qb * 128 + wv * 32;

  const unsigned short* Qbase = Qh + ((size_t)bh * N_ + q0) * D_;
  const unsigned short* Kbase = Kh + (size_t)bh * N_ * D_;
  const unsigned short* Vbase = Vt + (size_t)bh * D_ * N_;

  // Q as B-operand: lane holds Q[qf*16 + c][dblk*32 + g*8 + j]
  s16x8 qfrag[2][2];
  #pragma unroll
  for (int qf = 0; qf < 2; ++qf)
    #pragma unroll
    for (int dblk = 0; dblk < 2; ++dblk)
      qfrag[qf][dblk] =
          *(const s16x8*)&Qbase[(size_t)(qf * 16 + c) * D_ + dblk * 32 + g * 8];

  f32x4 O[2][4];
  float mrow[2], lrow[2];
  #pragma unroll
  for (int qf = 0; qf < 2; ++qf) {
    #pragma unroll
    for (int db = 0; db < 4; ++db) O[qf][db] = (f32x4){0.f, 0.f, 0.f, 0.f};
    mrow[qf] = -1e30f; lrow[qf] = 0.f;
  }

#define STAGE(buf, t)                                                          \
  do {                                                                         \
    const int kv0s = (t) * 128;                                                \
    _Pragma("unroll")                                                          \
    for (int i = 0; i < 4; ++i) {                                              \
      int row = wv * 32 + i * 8 + (lane >> 3);                                 \
      int un = (lane & 7) ^ (row & 7);                                         \
      __builtin_amdgcn_global_load_lds(                                        \
          (const __attribute__((address_space(1))) void*)(Kbase +              \
              (size_t)(kv0s + row) * 64 + un * 8),                             \
          (__attribute__((address_space(3))) void*)(&Ks[buf][(wv * 32 + i * 8) * 64]), \
          16, 0, 0);                                                           \
    }                                                                          \
    _Pragma("unroll")                                                          \
    for (int jj = 0; jj < 4; ++jj) {                                           \
      int dd = wv * 16 + jj * 4 + (lane >> 4);                                 \
      int un = (lane & 15) ^ (dd & 7);                                         \
      __builtin_amdgcn_global_load_lds(                                        \
          (const __attribute__((address_space(1))) void*)(Vbase +              \
              (size_t)dd * N_ + kv0s + un * 8),                                \
          (__attribute__((address_space(3))) void*)(&Vs[buf][(wv * 16 + jj * 4) * 128]), \
          16, 0, 0);                                                           \
    }                                                                          \
  } while (0)

  STAGE(0, 0);
  __syncthreads();

  for (int t = 0; t < 16; ++t) {
    const int cur = t & 1;
    if (t < 15) STAGE(cur ^ 1, t + 1);

    // --- S^T = K * Q^T : lane holds S[k = kb*16 + g*4 + r][q = c] ---
    f32x4 st[2][8];
    #pragma unroll
    for (int kb = 0; kb < 8; ++kb) {
      s16x8 k0 = *(const s16x8*)&Ks[cur][(kb * 16 + c) * 64 + (g ^ c7) * 8];
      s16x8 k1 = *(const s16x8*)&Ks[cur][(kb * 16 + c) * 64 + ((4 + g) ^ c7) * 8];
      #pragma unroll
      for (int qf = 0; qf < 2; ++qf) {
        f32x4 z = (f32x4){0.f, 0.f, 0.f, 0.f};
        z = __builtin_amdgcn_mfma_f32_16x16x32_bf16(k0, qfrag[qf][0], z, 0, 0, 0);
        st[qf][kb] = __builtin_amdgcn_mfma_f32_16x16x32_bf16(k1, qfrag[qf][1], st[qf][kb] = z, 0, 0, 0);
      }
    }

    // --- online softmax (exp2 domain; scale folded into Wq) + pack P ---
    u32 pf[2][4][4];
    #pragma unroll
    for (int qf = 0; qf < 2; ++qf) {
      float pm = st[qf][0][0];
      #pragma unroll
      for (int kb = 0; kb < 8; ++kb)
        #pragma unroll
        for (int r = 0; r < 4; ++r) pm = fmaxf(pm, st[qf][kb][r]);
      pm = fmaxf(pm, __shfl_xor(pm, 16));
      pm = fmaxf(pm, __shfl_xor(pm, 32));
      float mnew = fmaxf(mrow[qf], pm);
      float alpha = __builtin_amdgcn_exp2f(mrow[qf] - mnew);
      mrow[qf] = mnew;
      float rs = 0.f;
      #pragma unroll
      for (int kb = 0; kb < 8; ++kb)
        #pragma unroll
        for (int r = 0; r < 4; ++r) {
          float p = __builtin_amdgcn_exp2f(st[qf][kb][r] - mnew);
          rs += p;
          st[qf][kb][r] = p;
        }
      rs += __shfl_xor(rs, 16);
      rs += __shfl_xor(rs, 32);
      lrow[qf] = lrow[qf] * alpha + rs;
      #pragma unroll
      for (int db = 0; db < 4; ++db)
        #pragma unroll
        for (int r = 0; r < 4; ++r) O[qf][db][r] *= alpha;

      // pack to bf16 pairs, then exchange lane-bits with reg-bits:
      // source (lane g_s, reg (kb&1, h)) -> target (lane (kb&1, g_s>>1), reg (g_s&1, h))
      #pragma unroll
      for (int km = 0; km < 4; ++km) {
        u32 x00, x01, x10, x11;
        asm("v_cvt_pk_bf16_f32 %0, %1, %2" : "=v"(x00) : "v"(st[qf][2 * km][0]), "v"(st[qf][2 * km][1]));
        asm("v_cvt_pk_bf16_f32 %0, %1, %2" : "=v"(x01) : "v"(st[qf][2 * km][2]), "v"(st[qf][2 * km][3]));
        asm("v_cvt_pk_bf16_f32 %0, %1, %2" : "=v"(x10) : "v"(st[qf][2 * km + 1][0]), "v"(st[qf][2 * km + 1][1]));
        asm("v_cvt_pk_bf16_f32 %0, %1, %2" : "=v"(x11) : "v"(st[qf][2 * km + 1][2]), "v"(st[qf][2 * km + 1][3]));
        asm("v_permlane32_swap_b32 %0, %1" : "+v"(x00), "+v"(x10));
        asm("v_permlane32_swap_b32 %0, %1" : "+v"(x01), "+v"(x11));
        asm("v_permlane16_swap_b32 %0, %1" : "+v"(x00), "+v"(x10));
        asm("v_permlane16_swap_b32 %0, %1" : "+v"(x01), "+v"(x11));
        pf[qf][km][0] = x00; pf[qf][km][1] = x01;
        pf[qf][km][2] = x10; pf[qf][km][3] = x11;
      }
    }

    // --- O^T += V^T * P^T : A = V^T from LDS, B = packed P frags ---
    #pragma unroll
    for (int km = 0; km < 4; ++km) {
      union { u32x4 u; s16x8 s; } b0, b1;
      b0.u = (u32x4){pf[0][km][0], pf[0][km][1], pf[0][km][2], pf[0][km][3]};
      b1.u = (u32x4){pf[1][km][0], pf[1][km][1], pf[1][km][2], pf[1][km][3]};
      #pragma unroll
      for (int db = 0; db < 4; ++db) {
        s16x8 vf = *(const s16x8*)&Vs[cur][(db * 16 + c) * 128 + ((km * 4 + g) ^ c7) * 8];
        O[0][db] = __builtin_amdgcn_mfma_f32_16x16x32_bf16(vf, b0.s, O[0][db], 0, 0, 0);
        O[1][db] = __builtin_amdgcn_mfma_f32_16x16x32_bf16(vf, b1.s, O[1][db], 0, 0, 0);
      }
    }
    __syncthreads();
  }
#undef STAGE

  // epilogue: O^T frag (db,qf): lane holds rows d = db*16 + g*4 + r, col q = c
  #pragma unroll
  for (int qf = 0; qf < 2; ++qf) {
    float linv = 1.0f / lrow[qf];
    size_t rowoff = ((size_t)(b * N_ + q0 + qf * 16 + c)) * C_ + h * 64;
    #pragma unroll
    for (int db = 0; db < 4; ++db) {
      u32 d0, d1;
      float v0 = O[qf][db][0] * linv, v1 = O[qf][db][1] * linv;
      float v2 = O[qf][db][2] * linv, v3 = O[qf][db][3] * linv;
      asm("v_cvt_pk_bf16_f32 %0, %1, %2" : "=v"(d0) : "v"(v0), "v"(v1));
      asm("v_cvt_pk_bf16_f32 %0, %1, %2" : "=v"(d1) : "v"(v2), "v"(v3));
      uint2 st2; st2.x = d0; st2.y = d1;
      *(uint2*)&heads[rowoff + db * 16 + g * 4] = st2;
    }
  }
}

// ---------------------------------------------------------------------------
extern "C" void kernel_launch(void* const* d_in, const int* in_sizes, int n_in,
                              void* d_out, int out_size, void* d_ws, size_t ws_size,
                              hipStream_t stream) {
  const float* x  = (const float*)d_in[0];
  const float* Wq = (const float*)d_in[1];
  const float* Wk = (const float*)d_in[2];
  const float* Wv = (const float*)d_in[3];
  const float* Wo = (const float*)d_in[4];
  float* out = (float*)d_out;

  char* ws = (char*)d_ws;
  unsigned short* WtQKV = (unsigned short*)(ws);
  unsigned short* WtO   = (unsigned short*)(ws + 6291456);
  unsigned short* Qh    = (unsigned short*)(ws + 8388608);
  unsigned short* Kh    = (unsigned short*)(ws + 16777216);
  unsigned short* Vt    = (unsigned short*)(ws + 25165824);
  unsigned short* heads = (unsigned short*)(ws + 33554432);

  wtrans_kernel<<<dim3(1024), dim3(256), 0, stream>>>(Wq, Wk, Wv, Wo, WtQKV, WtO);
  gemm_kernel<0><<<dim3(32, 24), dim3(256), 0, stream>>>(x, WtQKV, Qh, Kh, Vt, nullptr);
  attn_kernel<<<dim3(512), dim3(256), 0, stream>>>(Qh, Kh, Vt, heads);
  gemm_kernel<1><<<dim3(32, 8), dim3(256), 0, stream>>>(heads, WtO, nullptr, nullptr, nullptr, out);
}

// Round 3
// 130.289 us; speedup vs baseline: 1.8616x; 1.0038x over previous
//
#include <hip/hip_runtime.h>

typedef __attribute__((ext_vector_type(4))) float f32x4;
typedef __attribute__((ext_vector_type(8))) short s16x8;
typedef unsigned int u32;
typedef __attribute__((ext_vector_type(4))) unsigned int u32x4;

#define B_ 2
#define N_ 2048
#define C_ 1024
#define H_ 16
#define D_ 64

__device__ __forceinline__ unsigned short f2bf(float f) {
  union { float f; unsigned u; } v; v.f = f;
  unsigned r = v.u + 0x7fffu + ((v.u >> 16) & 1u);
  return (unsigned short)(r >> 16);
}

// ---------------------------------------------------------------------------
// Blocks [0,1024): transpose + convert weights to bf16 (Wq gets 1/8*log2e).
// Blocks [1024,3072): convert x (f32) -> xb (bf16), 2048 elems/block.
// ---------------------------------------------------------------------------
__global__ __launch_bounds__(256) void wtrans_kernel(
    const float* __restrict__ Wq, const float* __restrict__ Wk,
    const float* __restrict__ Wv, const float* __restrict__ Wo,
    unsigned short* __restrict__ WtQKV, unsigned short* __restrict__ WtO,
    const float* __restrict__ xsrc, unsigned short* __restrict__ xb) {
  const int t = threadIdx.x;
  if (blockIdx.x >= 1024) {
    int i = (blockIdx.x - 1024) * 2048 + t * 8;
    float4 f0 = *(const float4*)&xsrc[i];
    float4 f1 = *(const float4*)&xsrc[i + 4];
    u32 p0, p1, p2, p3;
    asm("v_cvt_pk_bf16_f32 %0, %1, %2" : "=v"(p0) : "v"(f0.x), "v"(f0.y));
    asm("v_cvt_pk_bf16_f32 %0, %1, %2" : "=v"(p1) : "v"(f0.z), "v"(f0.w));
    asm("v_cvt_pk_bf16_f32 %0, %1, %2" : "=v"(p2) : "v"(f1.x), "v"(f1.y));
    asm("v_cvt_pk_bf16_f32 %0, %1, %2" : "=v"(p3) : "v"(f1.z), "v"(f1.w));
    uint4 o; o.x = p0; o.y = p1; o.z = p2; o.w = p3;
    *(uint4*)&xb[i] = o;
    return;
  }
  __shared__ float lds[64][65];
  const int w = blockIdx.x >> 8;
  const int tile = blockIdx.x & 255;
  const int c0 = (tile >> 4) * 64, d0 = (tile & 15) * 64;
  const float* W = (w == 0) ? Wq : (w == 1) ? Wk : (w == 2) ? Wv : Wo;
  const float scale = (w == 0) ? 0.125f * 1.4426950408889634f : 1.0f;
  #pragma unroll
  for (int p = 0; p < 16; ++p) {
    int i = p * 256 + t; int r = i >> 6, cc = i & 63;
    lds[r][cc] = W[(size_t)(c0 + r) * 1024 + d0 + cc];
  }
  __syncthreads();
  #pragma unroll
  for (int p = 0; p < 16; ++p) {
    int i = p * 256 + t; int r = i >> 6, cc = i & 63;
    unsigned short v = f2bf(lds[cc][r] * scale);
    if (w < 3) WtQKV[(size_t)(w * 1024 + d0 + r) * 1024 + c0 + cc] = v;
    else       WtO[(size_t)(d0 + r) * 1024 + c0 + cc] = v;
  }
}

// ---------------------------------------------------------------------------
// GEMM C[M][N] = A[M][1024] * Bt[N][1024]^T. A bf16 (k-contig), 128x128 tile,
// BK=32, 4 waves (2x2), global_load_lds staging both operands, explicit LDS
// double-buffer, one barrier per k-step, 2-bit XOR source swizzle.
// MODE 0: epilogue scatters bf16 Q/K/V.  MODE 1: epilogue writes f32 C.
// ---------------------------------------------------------------------------
template <int MODE>
__global__ __launch_bounds__(256, 2) void gemm_kernel(
    const unsigned short* __restrict__ A, const unsigned short* __restrict__ Bt,
    unsigned short* __restrict__ Qh, unsigned short* __restrict__ Kh,
    unsigned short* __restrict__ Vt, float* __restrict__ Cf) {
  __shared__ unsigned short As[2][128 * 32];
  __shared__ unsigned short Bs[2][128 * 32];
  const int tid = threadIdx.x;
  const int lane = tid & 63, wv = tid >> 6;
  const int g = lane >> 4, c = lane & 15;
  const int wr = wv >> 1, wc = wv & 1;
  const int am0 = blockIdx.x * 128;
  const int bn0 = blockIdx.y * 128;

  f32x4 acc[4][4];
  #pragma unroll
  for (int m = 0; m < 4; m++)
    #pragma unroll
    for (int n = 0; n < 4; n++) acc[m][n] = (f32x4){0.f, 0.f, 0.f, 0.f};

  const int srow = (lane >> 2);               // 0..15 within wave-issue
  const int schunk = (lane & 3) ^ (srow & 3); // 2-bit source swizzle

#define GSTAGE(buf, k0s)                                                       \
  do {                                                                         \
    _Pragma("unroll")                                                          \
    for (int i = 0; i < 2; ++i) {                                              \
      int row = i * 64 + wv * 16 + srow;                                       \
      __builtin_amdgcn_global_load_lds(                                        \
          (const __attribute__((address_space(1))) void*)(                     \
              A + (size_t)(am0 + row) * 1024 + (k0s) + schunk * 8),            \
          (__attribute__((address_space(3))) void*)(&As[buf][(i * 64 + wv * 16) * 32]), \
          16, 0, 0);                                                           \
      __builtin_amdgcn_global_load_lds(                                        \
          (const __attribute__((address_space(1))) void*)(                     \
              Bt + (size_t)(bn0 + row) * 1024 + (k0s) + schunk * 8),           \
          (__attribute__((address_space(3))) void*)(&Bs[buf][(i * 64 + wv * 16) * 32]), \
          16, 0, 0);                                                           \
    }                                                                          \
  } while (0)

  GSTAGE(0, 0);
  __syncthreads();
  for (int kt = 0; kt < 32; ++kt) {
    const int cur = kt & 1;
    if (kt < 31) GSTAGE(cur ^ 1, (kt + 1) * 32);
    s16x8 af[4], bfr[4];
    #pragma unroll
    for (int m = 0; m < 4; m++) {
      int R = wr * 64 + m * 16 + c;
      af[m] = *(const s16x8*)&As[cur][R * 32 + ((g ^ (R & 3)) << 3)];
    }
    #pragma unroll
    for (int n = 0; n < 4; n++) {
      int R = wc * 64 + n * 16 + c;
      bfr[n] = *(const s16x8*)&Bs[cur][R * 32 + ((g ^ (R & 3)) << 3)];
    }
    __builtin_amdgcn_s_setprio(1);
    #pragma unroll
    for (int m = 0; m < 4; m++)
      #pragma unroll
      for (int n = 0; n < 4; n++)
        acc[m][n] = __builtin_amdgcn_mfma_f32_16x16x32_bf16(af[m], bfr[n], acc[m][n], 0, 0, 0);
    __builtin_amdgcn_s_setprio(0);
    __syncthreads();
  }
#undef GSTAGE

  #pragma unroll
  for (int m = 0; m < 4; m++) {
    #pragma unroll
    for (int n = 0; n < 4; n++) {
      f32x4 v = acc[m][n];
      int colg = bn0 + wc * 64 + n * 16 + c;
      #pragma unroll
      for (int r = 0; r < 4; ++r) {
        int row = am0 + wr * 64 + m * 16 + g * 4 + r;
        if (MODE == 1) {
          Cf[(size_t)row * 1024 + colg] = v[r];
        } else {
          int tensor = colg >> 10, cc = colg & 1023;
          int hh = cc >> 6, dd = cc & 63;
          int bb = row >> 11, tok = row & 2047;
          unsigned short val = f2bf(v[r]);
          if (tensor == 0)
            Qh[(((size_t)bb * H_ + hh) * N_ + tok) * D_ + dd] = val;
          else if (tensor == 1)
            Kh[(((size_t)bb * H_ + hh) * N_ + tok) * D_ + dd] = val;
          else
            Vt[(((size_t)bb * H_ + hh) * D_ + dd) * N_ + tok] = val;
        }
      }
    }
  }
}

// ---------------------------------------------------------------------------
// Flash attention, swapped-QK^T in-register softmax. Grid 1024 (XCD-swizzled):
// 32 bh x 32 q-blocks of 64 rows; 4 waves x 16 q-rows. KVBLK=64.
// K [64][64] / V^T [64][64] in LDS via global_load_lds, double-buffered,
// 3-bit XOR swizzle (128B rows). P in registers via cvt_pk + permlane swaps.
// Defer-max (THR=8 in log2 domain) skips O-rescale on most tiles.
// ---------------------------------------------------------------------------
__global__ __launch_bounds__(256, 4) void attn_kernel(
    const unsigned short* __restrict__ Qh, const unsigned short* __restrict__ Kh,
    const unsigned short* __restrict__ Vt, unsigned short* __restrict__ heads) {
  __shared__ unsigned short Ks[2][64 * 64];
  __shared__ unsigned short Vs[2][64 * 64];
  const int tid = threadIdx.x;
  const int lane = tid & 63, wv = tid >> 6;
  const int g = lane >> 4, c = lane & 15;
  const int c7 = c & 7;
  int bid = blockIdx.x;
  bid = (bid & 7) * 128 + (bid >> 3);  // XCD-chunked swizzle, 1024 % 8 == 0
  const int bh = bid >> 5, qb = bid & 31;
  const int b = bh >> 4, h = bh & 15;
  const int q0 = qb * 64 + wv * 16;

  const unsigned short* Qbase = Qh + ((size_t)bh * N_ + q0) * D_;
  const unsigned short* Kbase = Kh + (size_t)bh * N_ * D_;
  const unsigned short* Vbase = Vt + (size_t)bh * D_ * N_;

  // Q as B-operand: lane holds Q[c][dblk*32 + g*8 + j]
  s16x8 qfrag[2];
  #pragma unroll
  for (int dblk = 0; dblk < 2; ++dblk)
    qfrag[dblk] = *(const s16x8*)&Qbase[(size_t)c * D_ + dblk * 32 + g * 8];

  f32x4 O[4];
  #pragma unroll
  for (int db = 0; db < 4; ++db) O[db] = (f32x4){0.f, 0.f, 0.f, 0.f};
  float mrow = -1e30f, lrow = 0.f;

#define STAGE(buf, t)                                                          \
  do {                                                                         \
    const int kv0s = (t) * 64;                                                 \
    _Pragma("unroll")                                                          \
    for (int i = 0; i < 2; ++i) {                                              \
      int row = wv * 16 + i * 8 + (lane >> 3);                                 \
      int un = (lane & 7) ^ (row & 7);                                         \
      __builtin_amdgcn_global_load_lds(                                        \
          (const __attribute__((address_space(1))) void*)(Kbase +              \
              (size_t)(kv0s + row) * 64 + un * 8),                             \
          (__attribute__((address_space(3))) void*)(&Ks[buf][(wv * 16 + i * 8) * 64]), \
          16, 0, 0);                                                           \
    }                                                                          \
    _Pragma("unroll")                                                          \
    for (int jj = 0; jj < 2; ++jj) {                                           \
      int dd = wv * 16 + jj * 8 + (lane >> 3);                                 \
      int un = (lane & 7) ^ (dd & 7);                                          \
      __builtin_amdgcn_global_load_lds(                                        \
          (const __attribute__((address_space(1))) void*)(Vbase +              \
              (size_t)dd * N_ + kv0s + un * 8),                                \
          (__attribute__((address_space(3))) void*)(&Vs[buf][(wv * 16 + jj * 8) * 64]), \
          16, 0, 0);                                                           \
    }                                                                          \
  } while (0)

  STAGE(0, 0);
  __syncthreads();

  for (int t = 0; t < 32; ++t) {
    const int cur = t & 1;
    if (t < 31) STAGE(cur ^ 1, t + 1);

    // --- S^T = K * Q^T : lane holds S[k = kb*16 + g*4 + r][q = c] ---
    f32x4 st[4];
    __builtin_amdgcn_s_setprio(1);
    #pragma unroll
    for (int kb = 0; kb < 4; ++kb) {
      s16x8 k0 = *(const s16x8*)&Ks[cur][(kb * 16 + c) * 64 + ((g ^ c7) << 3)];
      s16x8 k1 = *(const s16x8*)&Ks[cur][(kb * 16 + c) * 64 + (((4 + g) ^ c7) << 3)];
      f32x4 z = (f32x4){0.f, 0.f, 0.f, 0.f};
      z = __builtin_amdgcn_mfma_f32_16x16x32_bf16(k0, qfrag[0], z, 0, 0, 0);
      st[kb] = __builtin_amdgcn_mfma_f32_16x16x32_bf16(k1, qfrag[1], z, 0, 0, 0);
    }
    __builtin_amdgcn_s_setprio(0);

    // --- online softmax (exp2 domain; 1/8*log2e folded into Wq) ---
    float pm = st[0][0];
    #pragma unroll
    for (int kb = 0; kb < 4; ++kb)
      #pragma unroll
      for (int r = 0; r < 4; ++r) pm = fmaxf(pm, st[kb][r]);
    pm = fmaxf(pm, __shfl_xor(pm, 16));
    pm = fmaxf(pm, __shfl_xor(pm, 32));
    if (!__all(pm - mrow <= 8.0f)) {   // defer-max: rescale only on real growth
      float mnew = fmaxf(mrow, pm);
      float alpha = __builtin_amdgcn_exp2f(mrow - mnew);
      lrow *= alpha;
      #pragma unroll
      for (int db = 0; db < 4; ++db)
        #pragma unroll
        for (int r = 0; r < 4; ++r) O[db][r] *= alpha;
      mrow = mnew;
    }
    float rs = 0.f;
    #pragma unroll
    for (int kb = 0; kb < 4; ++kb)
      #pragma unroll
      for (int r = 0; r < 4; ++r) {
        float p = __builtin_amdgcn_exp2f(st[kb][r] - mrow);
        rs += p;
        st[kb][r] = p;
      }
    rs += __shfl_xor(rs, 16);
    rs += __shfl_xor(rs, 32);
    lrow += rs;

    // pack P to bf16 + lane/reg-bit exchange -> PV B-fragments
    u32 pf[2][4];
    #pragma unroll
    for (int km = 0; km < 2; ++km) {
      u32 x00, x01, x10, x11;
      asm("v_cvt_pk_bf16_f32 %0, %1, %2" : "=v"(x00) : "v"(st[2 * km][0]), "v"(st[2 * km][1]));
      asm("v_cvt_pk_bf16_f32 %0, %1, %2" : "=v"(x01) : "v"(st[2 * km][2]), "v"(st[2 * km][3]));
      asm("v_cvt_pk_bf16_f32 %0, %1, %2" : "=v"(x10) : "v"(st[2 * km + 1][0]), "v"(st[2 * km + 1][1]));
      asm("v_cvt_pk_bf16_f32 %0, %1, %2" : "=v"(x11) : "v"(st[2 * km + 1][2]), "v"(st[2 * km + 1][3]));
      asm("v_permlane32_swap_b32 %0, %1" : "+v"(x00), "+v"(x10));
      asm("v_permlane32_swap_b32 %0, %1" : "+v"(x01), "+v"(x11));
      asm("v_permlane16_swap_b32 %0, %1" : "+v"(x00), "+v"(x10));
      asm("v_permlane16_swap_b32 %0, %1" : "+v"(x01), "+v"(x11));
      pf[km][0] = x00; pf[km][1] = x01; pf[km][2] = x10; pf[km][3] = x11;
    }

    // --- O^T += V^T * P^T ---
    __builtin_amdgcn_s_setprio(1);
    #pragma unroll
    for (int km = 0; km < 2; ++km) {
      union { u32x4 u; s16x8 s; } bb_;
      bb_.u = (u32x4){pf[km][0], pf[km][1], pf[km][2], pf[km][3]};
      #pragma unroll
      for (int db = 0; db < 4; ++db) {
        s16x8 vf = *(const s16x8*)&Vs[cur][(db * 16 + c) * 64 + (((km * 4 + g) ^ c7) << 3)];
        O[db] = __builtin_amdgcn_mfma_f32_16x16x32_bf16(vf, bb_.s, O[db], 0, 0, 0);
      }
    }
    __builtin_amdgcn_s_setprio(0);
    __syncthreads();
  }
#undef STAGE

  // epilogue: lane holds O^T[d = db*16 + g*4 + r][q = c]
  float linv = 1.0f / lrow;
  size_t rowoff = ((size_t)(b * N_ + q0 + c)) * C_ + h * 64;
  #pragma unroll
  for (int db = 0; db < 4; ++db) {
    u32 d0, d1;
    float v0 = O[db][0] * linv, v1 = O[db][1] * linv;
    float v2 = O[db][2] * linv, v3 = O[db][3] * linv;
    asm("v_cvt_pk_bf16_f32 %0, %1, %2" : "=v"(d0) : "v"(v0), "v"(v1));
    asm("v_cvt_pk_bf16_f32 %0, %1, %2" : "=v"(d1) : "v"(v2), "v"(v3));
    uint2 st2; st2.x = d0; st2.y = d1;
    *(uint2*)&heads[rowoff + db * 16 + g * 4] = st2;
  }
}

// ---------------------------------------------------------------------------
extern "C" void kernel_launch(void* const* d_in, const int* in_sizes, int n_in,
                              void* d_out, int out_size, void* d_ws, size_t ws_size,
                              hipStream_t stream) {
  const float* x  = (const float*)d_in[0];
  const float* Wq = (const float*)d_in[1];
  const float* Wk = (const float*)d_in[2];
  const float* Wv = (const float*)d_in[3];
  const float* Wo = (const float*)d_in[4];
  float* out = (float*)d_out;

  char* ws = (char*)d_ws;
  unsigned short* WtQKV = (unsigned short*)(ws);
  unsigned short* WtO   = (unsigned short*)(ws + 6291456);
  unsigned short* Qh    = (unsigned short*)(ws + 8388608);
  unsigned short* Kh    = (unsigned short*)(ws + 16777216);
  unsigned short* Vt    = (unsigned short*)(ws + 25165824);
  unsigned short* heads = (unsigned short*)(ws + 33554432);
  // xb aliases heads: xb is dead after gemm<0>, heads born at attn.
  unsigned short* xb    = (unsigned short*)(ws + 33554432);

  wtrans_kernel<<<dim3(3072), dim3(256), 0, stream>>>(Wq, Wk, Wv, Wo, WtQKV, WtO, x, xb);
  gemm_kernel<0><<<dim3(32, 24), dim3(256), 0, stream>>>(xb, WtQKV, Qh, Kh, Vt, nullptr);
  attn_kernel<<<dim3(1024), dim3(256), 0, stream>>>(Qh, Kh, Vt, heads);
  gemm_kernel<1><<<dim3(32, 8), dim3(256), 0, stream>>>(heads, WtO, nullptr, nullptr, nullptr, out);
}